// Round 1
// 298.158 us; speedup vs baseline: 1.1101x; 1.1101x over previous
//
#include <hip/hip_runtime.h>

#define N_NODES 100000
#define E_EDGES 1600000
#define D 128
#define FCHUNK 2048        // edges per fill block
#define RSIZE 12500        // nodes per dst-range (N/8), XCD-local atomics
#define PAD 136            // LDS row stride (ushorts): 272B = 16B-aligned, frag reads ~conflict-free
#define GEMM_BLKS 1563     // (N+63)/64
#define FILL_BLKS (((E_EDGES + FCHUNK - 1) / FCHUNK) * 8)   // 782*8 = 6256

typedef __attribute__((ext_vector_type(8))) short short8;
typedef __attribute__((ext_vector_type(8))) unsigned short ushort8v;
typedef __attribute__((ext_vector_type(4))) float f32x4;

// ---------- threefry2x32, key=(0,42), ctr=(0,i); JAX partitionable 32-bit: x0^x1 ----------
__device__ __forceinline__ unsigned int rotl32(unsigned int x, int r) {
  return (x << r) | (x >> (32 - r));
}

__device__ __forceinline__ unsigned int threefry_bits(unsigned int ctr) {
  const unsigned int ks0 = 0u, ks1 = 42u;
  const unsigned int ks2 = ks0 ^ ks1 ^ 0x1BD11BDAu;
  unsigned int x0 = ks0;
  unsigned int x1 = ctr + ks1;
#define TF_ROUND(R) { x0 += x1; x1 = rotl32(x1, R); x1 ^= x0; }
  TF_ROUND(13) TF_ROUND(15) TF_ROUND(26) TF_ROUND(6)
  x0 += ks1; x1 += ks2 + 1u;
  TF_ROUND(17) TF_ROUND(29) TF_ROUND(16) TF_ROUND(24)
  x0 += ks2; x1 += ks0 + 2u;
  TF_ROUND(13) TF_ROUND(15) TF_ROUND(26) TF_ROUND(6)
  x0 += ks0; x1 += ks1 + 3u;
  TF_ROUND(17) TF_ROUND(29) TF_ROUND(16) TF_ROUND(24)
  x0 += ks1; x1 += ks2 + 4u;
  TF_ROUND(13) TF_ROUND(15) TF_ROUND(26) TF_ROUND(6)
  x0 += ks2; x1 += ks0 + 5u;
#undef TF_ROUND
  return x0 ^ x1;
}

__device__ __forceinline__ unsigned short f2bf(float f) {
  unsigned int u = __float_as_uint(f);
  u = (u + 0x7FFFu + ((u >> 16) & 1u)) >> 16;   // RNE
  return (unsigned short)u;
}
__device__ __forceinline__ float bf2f_lo(unsigned int v) {
  return __uint_as_float(v << 16);
}
__device__ __forceinline__ float bf2f_hi(unsigned int v) {
  return __uint_as_float(v & 0xFFFF0000u);
}

// ---------- init: zero cursor + convert W to bf16 (once, transposed to [n][k]) ----------
__global__ __launch_bounds__(256) void k_init(const float* __restrict__ w,
                                              unsigned short* __restrict__ wbf,
                                              int* __restrict__ cursor) {
  int t = blockIdx.x * 256 + threadIdx.x;
  if (t < 128 * 128) {
    int k = t >> 7;          // w is [k][n] row-major
    int n = t & 127;
    wbf[n * 128 + k] = f2bf(w[t]);
  }
  for (int i = t; i < N_NODES; i += 128 * 256) cursor[i] = 0;
}

// ---------- fused: gemm (blocks 0..GEMM_BLKS-1) + slot-CSR fill (rest) ----------
// Fill's cursor atomics double as the degree histogram (dinv = rsqrt(cursor+1) later),
// so the old deg histogram + 2 scan kernels are gone entirely.
__global__ __launch_bounds__(256) void k_fused(const float* __restrict__ x,
                                               const unsigned short* __restrict__ wbf,
                                               unsigned short* __restrict__ h,
                                               const int* __restrict__ ei,
                                               int* __restrict__ cursor,
                                               int* __restrict__ slots,
                                               int cap) {
  __shared__ unsigned short Wl[128 * PAD];   // [n][k]
  __shared__ unsigned short Xl[64 * PAD];    // [m][k]; reused as output bounce buffer
  const int t = threadIdx.x;

  if (blockIdx.x >= GEMM_BLKS) {
    const int b    = blockIdx.x - GEMM_BLKS;
    const int r    = b & 7;                  // dst range -> stable XCD mapping
    const int base = (b >> 3) * FCHUNK;
    const int lo   = r * RSIZE;
    const int hi   = lo + RSIZE;
#pragma unroll
    for (int i = 0; i < FCHUNK / 256; ++i) {
      int e = base + i * 256 + t;
      if (e < E_EDGES) {
        int d = ei[E_EDGES + e];             // dst
        if (d >= lo && d < hi) {
          int s = ei[e];                     // src
          int pos = atomicAdd(&cursor[d], 1);
          if (pos < cap) slots[d * cap + pos] = s;
        }
      }
    }
    return;
  }

  const int row0 = blockIdx.x * 64;

  // stage W from pre-converted bf16: 16B/lane, coalesced (16 lanes cover one 256B row)
#pragma unroll
  for (int i = 0; i < 8; ++i) {
    int u  = t + i * 256;        // 0..2047 16B-units
    int kg = u & 15;
    int n  = u >> 4;             // 0..127
    *(ushort8v*)&Wl[n * PAD + kg * 8] = *(const ushort8v*)&wbf[n * 128 + kg * 8];
  }
  // stage X: 64 rows x 128 k, f32 -> bf16
  const float4* x4 = (const float4*)x;
#pragma unroll
  for (int i = 0; i < 8; ++i) {
    int id = t + i * 256;
    int r  = id >> 5;
    int c4 = id & 31;
    int row = row0 + r; if (row >= N_NODES) row = N_NODES - 1;
    float4 v = x4[(long long)row * 32 + c4];
    ushort4 p;
    p.x = f2bf(v.x); p.y = f2bf(v.y); p.z = f2bf(v.z); p.w = f2bf(v.w);
    *(ushort4*)&Xl[r * PAD + c4 * 4] = p;
  }
  __syncthreads();

  const int wv   = t >> 6;
  const int l    = t & 63;
  const int quad = l >> 4;
  const int ln16 = l & 15;
  const int m0   = wv * 16;

  short8 a[4];
#pragma unroll
  for (int kt = 0; kt < 4; ++kt)
    a[kt] = *(const short8*)&Xl[(m0 + ln16) * PAD + kt * 32 + quad * 8];

  // each wave owns Xl rows [m0, m0+16): a-frags are in registers now, so we can
  // scribble results back into our own rows without a barrier.
#pragma unroll
  for (int nt = 0; nt < 8; ++nt) {
    f32x4 acc = {0.f, 0.f, 0.f, 0.f};
#pragma unroll
    for (int kt = 0; kt < 4; ++kt) {
      short8 b = *(const short8*)&Wl[(nt * 16 + ln16) * PAD + kt * 32 + quad * 8];
      acc = __builtin_amdgcn_mfma_f32_16x16x32_bf16(a[kt], b, acc, 0, 0, 0);
    }
#pragma unroll
    for (int r = 0; r < 4; ++r)
      Xl[(m0 + quad * 4 + r) * PAD + nt * 16 + ln16] = f2bf(acc[r]);
  }

  // coalesced writeback: 16 lanes cover one 256B h row
#pragma unroll
  for (int v = 0; v < 4; ++v) {
    int idx = v * 64 + l;        // 0..255
    int rr  = idx >> 4;          // row in wave tile
    int ch  = idx & 15;          // 16B chunk
    int row = row0 + m0 + rr;
    if (row < N_NODES)
      *(ushort8v*)&h[(long long)row * D + ch * 8] = *(const ushort8v*)&Xl[(m0 + rr) * PAD + ch * 8];
  }
}

// ---------- aggregate: quarter-wave per edge, 2 edges in flight per quarter ----------
__global__ __launch_bounds__(256) void k_agg(const int* __restrict__ cursor,
                                             const int* __restrict__ slots,
                                             const unsigned short* __restrict__ h,
                                             const float* __restrict__ bias,
                                             float* __restrict__ out,
                                             int cap) {
  const int t = threadIdx.x;
  const int n = blockIdx.x * 4 + (t >> 6);
  const int lane = t & 63;
  const int q  = lane >> 4;       // quarter 0..3
  const int li = lane & 15;       // lane-in-quarter; owns cols li*8..li*8+7
  const uint4* hq = (const uint4*)h;   // 16 uint4 per row
  int cnt = cursor[n];
  float dn = rsqrtf((float)(cnt + 1));
  if (cnt > cap) cnt = cap;
  const int ebase = n * cap;
  float accA[8], accB[8];
#pragma unroll
  for (int j = 0; j < 8; ++j) { accA[j] = 0.f; accB[j] = 0.f; }

  for (int e = q; e < cnt; e += 8) {
    int s = slots[ebase + e];
    float wgt = rsqrtf((float)(cursor[s] + 1)) * dn;
    uint4 v = hq[(long long)s * 16 + li];
    int e2 = e + 4;
    if (e2 < cnt) {
      int s2 = slots[ebase + e2];
      float wgt2 = rsqrtf((float)(cursor[s2] + 1)) * dn;
      uint4 v2 = hq[(long long)s2 * 16 + li];
      accB[0] = fmaf(bf2f_lo(v2.x), wgt2, accB[0]);
      accB[1] = fmaf(bf2f_hi(v2.x), wgt2, accB[1]);
      accB[2] = fmaf(bf2f_lo(v2.y), wgt2, accB[2]);
      accB[3] = fmaf(bf2f_hi(v2.y), wgt2, accB[3]);
      accB[4] = fmaf(bf2f_lo(v2.z), wgt2, accB[4]);
      accB[5] = fmaf(bf2f_hi(v2.z), wgt2, accB[5]);
      accB[6] = fmaf(bf2f_lo(v2.w), wgt2, accB[6]);
      accB[7] = fmaf(bf2f_hi(v2.w), wgt2, accB[7]);
    }
    accA[0] = fmaf(bf2f_lo(v.x), wgt, accA[0]);
    accA[1] = fmaf(bf2f_hi(v.x), wgt, accA[1]);
    accA[2] = fmaf(bf2f_lo(v.y), wgt, accA[2]);
    accA[3] = fmaf(bf2f_hi(v.y), wgt, accA[3]);
    accA[4] = fmaf(bf2f_lo(v.z), wgt, accA[4]);
    accA[5] = fmaf(bf2f_hi(v.z), wgt, accA[5]);
    accA[6] = fmaf(bf2f_lo(v.w), wgt, accA[6]);
    accA[7] = fmaf(bf2f_hi(v.w), wgt, accA[7]);
  }
#pragma unroll
  for (int j = 0; j < 8; ++j) {
    float a = accA[j] + accB[j];
    a += __shfl_xor(a, 16);
    a += __shfl_xor(a, 32);
    accA[j] = a;
  }
  // lane finalizes cols c0 = li*8 + q*2, c0+1
  float a0 = accA[q * 2];
  float a1 = accA[q * 2 + 1];
  // self loop
  unsigned int hv = ((const unsigned int*)h)[(long long)n * 64 + li * 4 + q];
  float w2 = dn * dn;
  a0 = fmaf(bf2f_lo(hv), w2, a0);
  a1 = fmaf(bf2f_hi(hv), w2, a1);
  // bias + relu
  float2 bb = ((const float2*)bias)[li * 4 + q];
  float r0 = fmaxf(a0 + bb.x, 0.f);
  float r1 = fmaxf(a1 + bb.y, 0.f);
  // dropout: keep <=> top bit of threefry bits is 0
  unsigned int i0 = (unsigned int)n * 128u + (unsigned int)(li * 8 + q * 2);
  unsigned int b0 = threefry_bits(i0);
  unsigned int b1 = threefry_bits(i0 + 1u);
  float2 res;
  res.x = (b0 & 0x80000000u) ? 0.0f : r0 * 2.0f;
  res.y = (b1 & 0x80000000u) ? 0.0f : r1 * 2.0f;
  ((float2*)out)[(long long)n * 64 + li * 4 + q] = res;
}

extern "C" void kernel_launch(void* const* d_in, const int* in_sizes, int n_in,
                              void* d_out, int out_size, void* d_ws, size_t ws_size,
                              hipStream_t stream) {
  const float* x    = (const float*)d_in[0];
  const int*   ei   = (const int*)d_in[1];
  const float* w    = (const float*)d_in[2];
  const float* bias = (const float*)d_in[3];
  float* out = (float*)d_out;

  char* p = (char*)d_ws;
  unsigned short* h   = (unsigned short*)p;  p += (size_t)N_NODES * D * 2;   // 25.6 MB
  unsigned short* wbf = (unsigned short*)p;  p += 128 * 128 * 2;             // 32 KB
  int* cursor = (int*)p;                     p += (size_t)100032 * 4;        // 400128 B (256B-aligned end)
  int* slots  = (int*)p;

  size_t used = (size_t)(p - (char*)d_ws);
  int cap = 64;                                               // max degree ~40 for Poisson(16) over 100K nodes
  if (used + (size_t)N_NODES * 64 * 4 > ws_size) cap = 48;
  if (used + (size_t)N_NODES * 48 * 4 > ws_size) cap = 32;

  k_init<<<128, 256, 0, stream>>>(w, wbf, cursor);
  k_fused<<<GEMM_BLKS + FILL_BLKS, 256, 0, stream>>>(x, wbf, h, ei, cursor, slots, cap);
  k_agg<<<N_NODES / 4, 256, 0, stream>>>(cursor, slots, h, bias, out, cap);
}